// Round 1
// baseline (521.440 us; speedup 1.0000x reference)
//
#include <hip/hip_runtime.h>

#define N_PTS 131072
#define DIM   128
#define KC    512
#define BLOCK 256
#define KB    4

__global__ __launch_bounds__(BLOCK, 2)
void kmeans_dist_argmin(const float* __restrict__ x,
                        const float* __restrict__ c,
                        float* __restrict__ dist,
                        float* __restrict__ assign_out) {
    __shared__ float csq[KC];

    const int tid = threadIdx.x;
    const int n   = blockIdx.x * BLOCK + tid;

    // ---- block-level centroid-norm precompute (2 rows/thread, tiny) ----
    for (int k = tid; k < KC; k += BLOCK) {
        const float* cr = c + (size_t)k * DIM;
        float s = 0.f;
        #pragma unroll 8
        for (int d = 0; d < DIM; ++d) s = fmaf(cr[d], cr[d], s);
        csq[k] = s;
    }
    __syncthreads();

    // ---- load this thread's point into registers (128 VGPRs) ----
    float xr[DIM];
    const float4* xv = reinterpret_cast<const float4*>(x + (size_t)n * DIM);
    #pragma unroll
    for (int j = 0; j < DIM / 4; ++j) {
        float4 v = xv[j];
        xr[4 * j + 0] = v.x;
        xr[4 * j + 1] = v.y;
        xr[4 * j + 2] = v.z;
        xr[4 * j + 3] = v.w;
    }
    float xsq = 0.f;
    #pragma unroll
    for (int d = 0; d < DIM; ++d) xsq = fmaf(xr[d], xr[d], xsq);

    float bestd = INFINITY;
    int   bestk = 0;

    // ---- main loop: K in chunks of KB; centroid reads are wave-uniform
    //      (scalar loads), x stays in VGPRs → 1 v_fma per element ----
    for (int k0 = 0; k0 < KC; k0 += KB) {
        float acc[KB];
        #pragma unroll
        for (int kk = 0; kk < KB; ++kk) acc[kk] = 0.f;

        #pragma unroll
        for (int d = 0; d < DIM; ++d) {
            #pragma unroll
            for (int kk = 0; kk < KB; ++kk) {
                acc[kk] = fmaf(xr[d], c[(size_t)(k0 + kk) * DIM + d], acc[kk]);
            }
        }

        #pragma unroll
        for (int kk = 0; kk < KB; ++kk) {
            const int k = k0 + kk;
            float dv = fmaf(-2.f, acc[kk], xsq + csq[k]);
            dist[(size_t)k * N_PTS + n] = dv;   // coalesced across lanes (n contiguous)
            if (dv < bestd) { bestd = dv; bestk = k; }  // strict < : first-min, matches jnp.argmin
        }
    }

    assign_out[n] = (float)bestk;
}

extern "C" void kernel_launch(void* const* d_in, const int* in_sizes, int n_in,
                              void* d_out, int out_size, void* d_ws, size_t ws_size,
                              hipStream_t stream) {
    const float* x = (const float*)d_in[0];   // [N, D] fp32
    const float* c = (const float*)d_in[1];   // [K, D] fp32
    float* dist       = (float*)d_out;                          // [K, N]
    float* assign_out = dist + (size_t)KC * N_PTS;              // [N] (as float)

    kmeans_dist_argmin<<<N_PTS / BLOCK, BLOCK, 0, stream>>>(x, c, dist, assign_out);
}

// Round 2
// 107.809 us; speedup vs baseline: 4.8367x; 4.8367x over previous
//
#include <hip/hip_runtime.h>

#define N_PTS 131072
#define DIM   128
#define KC    512
#define NT    4                 // n-tiles (of 16 points) per wave
#define WAVES 4
#define BLOCK (WAVES * 64)
#define PTS_PER_WG (WAVES * NT * 16)   // 256
#define KTILES (KC / 16)               // 32

typedef _Float16 half8 __attribute__((ext_vector_type(8)));
typedef float    f32x4 __attribute__((ext_vector_type(4)));

// ---------------- prep: centroids fp32 -> f16 hi/lo split + csq ----------------
__global__ __launch_bounds__(128)
void prep_centroids(const float* __restrict__ c,
                    _Float16* __restrict__ chi,
                    _Float16* __restrict__ clo,
                    float* __restrict__ csq) {
    const int k = blockIdx.x;     // one block per centroid
    const int d = threadIdx.x;    // 128 threads = dims
    float v = c[k * DIM + d];
    _Float16 hi = (_Float16)v;
    _Float16 lo = (_Float16)(v - (float)hi);   // v-hi exact in fp32
    chi[k * DIM + d] = hi;
    clo[k * DIM + d] = lo;

    float s = v * v;
    #pragma unroll
    for (int off = 1; off < 64; off <<= 1) s += __shfl_xor(s, off);
    __shared__ float red[2];
    if ((d & 63) == 0) red[d >> 6] = s;
    __syncthreads();
    if (d == 0) csq[k] = red[0] + red[1];
}

// ---------------- main: split-f16 MFMA distances + fused argmin ----------------
__global__ __launch_bounds__(BLOCK, 2)
void kmeans_mfma(const float* __restrict__ x,
                 const _Float16* __restrict__ chi,
                 const _Float16* __restrict__ clo,
                 const float* __restrict__ csq,
                 float* __restrict__ dist,
                 float* __restrict__ assign_out) {
    const int tid  = threadIdx.x;
    const int wave = tid >> 6;
    const int lane = tid & 63;
    const int col  = lane & 15;       // n within tile / k-row within A-tile
    const int g    = lane >> 4;       // lane group -> k-slot block (and C row group)
    const int n0   = blockIdx.x * PTS_PER_WG + wave * (NT * 16);

    // ---- B-frags: this wave's 64 points, hi/lo f16, resident in VGPRs ----
    // lane l holds dims [s*32 + g*8 .. +7] of point (n0 + t*16 + col)
    half8 bhi[NT][4], blo[NT][4];
    float xsq[NT];
    #pragma unroll
    for (int t = 0; t < NT; ++t) {
        const float* xp = x + (size_t)(n0 + t * 16 + col) * DIM;
        float s = 0.f;
        #pragma unroll
        for (int sb = 0; sb < 4; ++sb) {
            const int dbase = sb * 32 + g * 8;
            float4 v0 = *(const float4*)(xp + dbase);
            float4 v1 = *(const float4*)(xp + dbase + 4);
            float vv[8] = {v0.x, v0.y, v0.z, v0.w, v1.x, v1.y, v1.z, v1.w};
            half8 h, l;
            #pragma unroll
            for (int j = 0; j < 8; ++j) {
                _Float16 hh = (_Float16)vv[j];
                h[j] = hh;
                l[j] = (_Float16)(vv[j] - (float)hh);
                s = fmaf(vv[j], vv[j], s);
            }
            bhi[t][sb] = h;
            blo[t][sb] = l;
        }
        // lanes {p, p+16, p+32, p+48} hold disjoint 32-dim slices -> reduce
        s += __shfl_xor(s, 16);
        s += __shfl_xor(s, 32);
        xsq[t] = s;
    }

    float bestd[NT];
    int   bestk[NT];
    #pragma unroll
    for (int t = 0; t < NT; ++t) { bestd[t] = INFINITY; bestk[t] = 0; }

    for (int kt = 0; kt < KTILES; ++kt) {
        // A-frags: 16 centroids (rows kt*16+col), hi/lo, from L2-resident ws
        const int krow = kt * 16 + col;
        const _Float16* ah = chi + (size_t)krow * DIM + g * 8;
        const _Float16* al = clo + (size_t)krow * DIM + g * 8;
        half8 Ah[4], Al[4];
        #pragma unroll
        for (int sb = 0; sb < 4; ++sb) {
            Ah[sb] = *(const half8*)(ah + sb * 32);
            Al[sb] = *(const half8*)(al + sb * 32);
        }
        f32x4 cs4 = *(const f32x4*)(csq + kt * 16 + g * 4);

        #pragma unroll
        for (int t = 0; t < NT; ++t) {
            f32x4 acc = {0.f, 0.f, 0.f, 0.f};
            #pragma unroll
            for (int sb = 0; sb < 4; ++sb) {
                acc = __builtin_amdgcn_mfma_f32_16x16x32_f16(Ah[sb], bhi[t][sb], acc, 0, 0, 0);
                acc = __builtin_amdgcn_mfma_f32_16x16x32_f16(Ah[sb], blo[t][sb], acc, 0, 0, 0);
                acc = __builtin_amdgcn_mfma_f32_16x16x32_f16(Al[sb], bhi[t][sb], acc, 0, 0, 0);
            }
            const int ncol = n0 + t * 16 + col;
            #pragma unroll
            for (int r = 0; r < 4; ++r) {
                const int kr = kt * 16 + g * 4 + r;     // C row = (lane>>4)*4 + reg (m89-verified)
                float dv = fmaf(-2.f, acc[r], xsq[t] + cs4[r]);
                dist[(size_t)kr * N_PTS + ncol] = dv;
                if (dv < bestd[t]) { bestd[t] = dv; bestk[t] = kr; }  // k ascending -> first-min
            }
        }
    }

    // ---- cross-lane argmin over the 4 lane groups (each saw k%16 in g*4..g*4+3) ----
    #pragma unroll
    for (int t = 0; t < NT; ++t) {
        float d = bestd[t];
        int   k = bestk[t];
        #pragma unroll
        for (int off = 16; off < 64; off <<= 1) {
            float od = __shfl_xor(d, off);
            int   ok = __shfl_xor(k, off);
            if (od < d || (od == d && ok < k)) { d = od; k = ok; }
        }
        if (g == 0) assign_out[n0 + t * 16 + col] = (float)k;
    }
}

extern "C" void kernel_launch(void* const* d_in, const int* in_sizes, int n_in,
                              void* d_out, int out_size, void* d_ws, size_t ws_size,
                              hipStream_t stream) {
    const float* x = (const float*)d_in[0];   // [N, D]
    const float* c = (const float*)d_in[1];   // [K, D]
    float* dist       = (float*)d_out;                 // [K, N]
    float* assign_out = dist + (size_t)KC * N_PTS;     // [N] as float

    // ws: chi[KC*DIM] f16 | clo[KC*DIM] f16 | csq[KC] f32   (~264 KB)
    _Float16* chi = (_Float16*)d_ws;
    _Float16* clo = chi + (size_t)KC * DIM;
    float*    csq = (float*)(clo + (size_t)KC * DIM);

    prep_centroids<<<KC, DIM, 0, stream>>>(c, chi, clo, csq);
    kmeans_mfma<<<N_PTS / PTS_PER_WG, BLOCK, 0, stream>>>(x, chi, clo, csq, dist, assign_out);
}